// Round 1
// 792.975 us; speedup vs baseline: 1.2433x; 1.2433x over previous
//
#include <hip/hip_runtime.h>

// ---------------------------------------------------------------------------
// DenseGATLayer: LN1 -> fused QKV proj -> adj-masked MHA -> WO proj + residual
//                -> LN2 -> GELU FFN -> residual
// B=32 N=512 D=768 H=12 HD=64. bf16 MFMA, fp32 accumulation.
// R6: GEMMs were latency-bound (MfmaUtil 10%, HBM 7%, occ 20%): 2 barriers +
// vmcnt(0) drain per 32-K step exposed full load latency, and WN=128 tiles
// gave 1.5-3 blocks/CU. Now: double-buffered single-barrier K-loop (T3
// 2-phase: stage next tile before computing current), 128x128 block tile
// (WN=64, 32KB LDS, bigger grids), QKV fused into one N=2304 GEMM with
// CSPLIT epilogue routing into contiguous Rq/Rk/Rv, fp32-packed biases.
// ---------------------------------------------------------------------------

#define Bn 32
#define Nn 512
#define Dn 768
#define Hn 12
#define HDn 64
#define Mn (Bn * Nn)      // 16384 rows
#define DFn 3072          // FFN hidden
#define MCHUNK 8192       // FFN M-chunk rows (hidden = 50.3 MB -> Rq+Rk)

typedef unsigned short u16;
typedef unsigned long long u64;
typedef short bf16x8 __attribute__((ext_vector_type(8)));
typedef float f32x4 __attribute__((ext_vector_type(4)));
typedef unsigned short u16x8 __attribute__((ext_vector_type(8)));

__device__ __forceinline__ float b2f(u16 u) {
    return __uint_as_float(((unsigned int)u) << 16);
}
__device__ __forceinline__ u16 f2b(float f) {
    unsigned int u = __float_as_uint(f);
    u += 0x7fffu + ((u >> 16) & 1u);   // RNE
    return (u16)(u >> 16);
}
__device__ __forceinline__ float loadDyn(const void* p, size_t i, int f) {
    return f ? ((const float*)p)[i] : b2f(((const u16*)p)[i]);
}
__device__ __forceinline__ float gelu_exact(float x) {
    return 0.5f * x * (1.0f + erff(x * 0.70710678118654752f));
}

// async global->LDS, 16B/lane; LDS dest = wave-uniform base + lane*16.
__device__ __forceinline__ void gl_lds16(const u16* g, u16* l) {
    __builtin_amdgcn_global_load_lds(
        (const __attribute__((address_space(1))) void*)(unsigned long long)(const void*)g,
        (__attribute__((address_space(3))) void*)(unsigned)(unsigned long long)(void*)l,
        16, 0, 0);
}

// ---------------------------------------------------------------------------
// Dtype sniffer (bf16 vs fp32 inputs). flag=1 => fp32.
// ---------------------------------------------------------------------------
__global__ __launch_bounds__(256) void sniff_k(const u16* __restrict__ x,
                                               int* __restrict__ flag) {
    __shared__ int tot;
    if (threadIdx.x == 0) tot = 0;
    __syncthreads();
    int cnt = 0;
    for (int i = threadIdx.x; i < 131072; i += 256) {
        u16 u = x[i];
        cnt += ((u & 0x7F80) == 0x7F80) ? 1 : 0;
    }
    atomicAdd(&tot, cnt);
    __syncthreads();
    if (threadIdx.x == 0) *flag = (tot > 32) ? 1 : 0;
}

// ---------------------------------------------------------------------------
// Pack all bias vectors to fp32: [bq 768 | bk 768 | bv 768 | bo 768 |
// bf1 3072 | bf2 768] = 6912 floats. Removes dyn-dtype loads from GEMM epi.
// ---------------------------------------------------------------------------
__global__ __launch_bounds__(256) void pack_bias_k(
    const void* __restrict__ bq, const void* __restrict__ bk,
    const void* __restrict__ bv, const void* __restrict__ bo,
    const void* __restrict__ bf1, const void* __restrict__ bf2,
    float* __restrict__ out, const int* __restrict__ flagp) {
    const int f = *flagp;
    const int i = blockIdx.x * 256 + threadIdx.x;
    if (i >= 6912) return;
    const void* src;
    int off;
    if (i < 768)       { src = bq;  off = i; }
    else if (i < 1536) { src = bk;  off = i - 768; }
    else if (i < 2304) { src = bv;  off = i - 1536; }
    else if (i < 3072) { src = bo;  off = i - 2304; }
    else if (i < 6144) { src = bf1; off = i - 3072; }
    else               { src = bf2; off = i - 6144; }
    out[i] = loadDyn(src, off, f);
}

// ---------------------------------------------------------------------------
// adj -> bitmask: mask[row*8 + seg] bit j = (adj[row][seg*64+j] != 0).
// ---------------------------------------------------------------------------
__global__ __launch_bounds__(256) void mask_build_k(
    const int* __restrict__ adj, u64* __restrict__ mask) {
    const int idx = blockIdx.x * 256 + threadIdx.x;   // Mn*8 = 131072 ids
    const size_t base = (size_t)(idx >> 3) * Nn + (size_t)(idx & 7) * 64;
    const int4* p = (const int4*)(adj + base);
    u64 m = 0;
#pragma unroll
    for (int c = 0; c < 16; c++) {
        int4 a = p[c];
        if (a.x) m |= 1ull << (c * 4 + 0);
        if (a.y) m |= 1ull << (c * 4 + 1);
        if (a.z) m |= 1ull << (c * 4 + 2);
        if (a.w) m |= 1ull << (c * 4 + 3);
    }
    mask[idx] = m;
}

// ---------------------------------------------------------------------------
// Transpose raw weight -> canonical bf16: out[c][r] = in[r][c]
// ---------------------------------------------------------------------------
__global__ __launch_bounds__(256) void transpose_k(
    const void* __restrict__ in, u16* __restrict__ out, int R, int C,
    const int* __restrict__ flagp) {
    const int f = *flagp;
    __shared__ u16 tile[32][33];
    int c0 = blockIdx.x * 32, r0 = blockIdx.y * 32;
    int tx = threadIdx.x, ty = threadIdx.y;  // 32 x 8
#pragma unroll
    for (int i = 0; i < 32; i += 8)
        tile[ty + i][tx] = f2b(loadDyn(in, (size_t)(r0 + ty + i) * C + c0 + tx, f));
    __syncthreads();
#pragma unroll
    for (int i = 0; i < 32; i += 8)
        out[(size_t)(c0 + ty + i) * R + r0 + tx] = tile[tx][ty + i];
}

// ---------------------------------------------------------------------------
// V [b][n][h][d] -> Vt [b*H+h][d][n]
// ---------------------------------------------------------------------------
__global__ __launch_bounds__(256) void vtrans_k(
    const u16* __restrict__ v, u16* __restrict__ vt) {
    __shared__ u16 tile[32][33];
    const int bh = blockIdx.z;                 // b*Hn + h
    const int d0 = blockIdx.x * 32;            // 0 / 32
    const int n0 = blockIdx.y * 32;
    const int b = bh / Hn, h = bh % Hn;
    const int tx = threadIdx.x, ty = threadIdx.y;   // 32 x 8
#pragma unroll
    for (int i = 0; i < 32; i += 8)
        tile[ty + i][tx] =
            v[(size_t)(b * Nn + n0 + ty + i) * Dn + h * HDn + d0 + tx];
    __syncthreads();
#pragma unroll
    for (int i = 0; i < 32; i += 8)
        vt[((size_t)bh * HDn + d0 + ty + i) * Nn + n0 + tx] = tile[tx][ty + i];
}

// ---------------------------------------------------------------------------
// LayerNorm over D=768. 8 rows/block, 32 lanes/row, u16x8 vector loads.
// ---------------------------------------------------------------------------
template <int XDYN>
__global__ __launch_bounds__(256) void ln_k(
    const void* __restrict__ x, const void* __restrict__ g,
    const void* __restrict__ b, u16* __restrict__ y,
    const int* __restrict__ flagp) {
    const int f = *flagp;
    const int t = threadIdx.x;
    const int row = blockIdx.x * 8 + (t >> 5);
    const int l32 = t & 31;
    const size_t base = (size_t)row * Dn;
    float v[24];
    if (XDYN == 0 || f == 0) {   // bf16 path (ws buffers always bf16)
        const u16* xp = (const u16*)x;
#pragma unroll
        for (int kk = 0; kk < 3; kk++) {
            u16x8 a = *(const u16x8*)&xp[base + kk * 256 + l32 * 8];
#pragma unroll
            for (int e = 0; e < 8; e++) v[kk * 8 + e] = b2f(a[e]);
        }
    } else {
#pragma unroll
        for (int kk = 0; kk < 3; kk++)
#pragma unroll
            for (int e = 0; e < 8; e++)
                v[kk * 8 + e] = loadDyn(x, base + kk * 256 + l32 * 8 + e, f);
    }
    float s = 0.f;
#pragma unroll
    for (int i = 0; i < 24; i++) s += v[i];
#pragma unroll
    for (int off = 1; off <= 16; off <<= 1) s += __shfl_xor(s, off, 64);
    const float mu = s * (1.0f / Dn);
    float d2 = 0.f;
#pragma unroll
    for (int i = 0; i < 24; i++) { float d = v[i] - mu; d2 += d * d; }
#pragma unroll
    for (int off = 1; off <= 16; off <<= 1) d2 += __shfl_xor(d2, off, 64);
    const float rstd = rsqrtf(d2 * (1.0f / Dn) + 1e-5f);
#pragma unroll
    for (int kk = 0; kk < 3; kk++) {
        const int c0 = kk * 256 + l32 * 8;
        u16x8 o;
        if (f == 0) {
            u16x8 gv = *(const u16x8*)&((const u16*)g)[c0];
            u16x8 bv = *(const u16x8*)&((const u16*)b)[c0];
#pragma unroll
            for (int e = 0; e < 8; e++)
                o[e] = f2b((v[kk * 8 + e] - mu) * rstd * b2f(gv[e]) + b2f(bv[e]));
        } else {
#pragma unroll
            for (int e = 0; e < 8; e++)
                o[e] = f2b((v[kk * 8 + e] - mu) * rstd * loadDyn(g, c0 + e, f)
                           + loadDyn(b, c0 + e, f));
        }
        *(u16x8*)&y[base + c0] = o;
    }
}

// ---------------------------------------------------------------------------
// GEMM: C[moff+M][N] = epi( A[M][K] @ Bt[N][K]^T + bias (+res) ).
// Block tile 128 x (2*WN), BK=32, 4 waves (2x2); wave tile 64 x WN.
// R6: double-buffered LDS, ONE barrier per K-step. stage(next) issues
// global_load_lds into buf^1 BEFORE the ds_read+MFMA of buf, so the loads'
// latency hides under the compute; the barrier's implicit vmcnt(0)/lgkmcnt(0)
// drain at the top of the next iteration is the only wait.
// CSPLIT>0: output columns are routed in CSPLIT-wide regions to consecutive
// [M][CSPLIT] buffers (fused QKV -> contiguous Rq/Rk/Rv).
// ---------------------------------------------------------------------------
template <int ACT, int RES, int STORE, int WN, int CSPLIT>
__global__ __launch_bounds__(256, 3) void gemm_bt(
    const u16* __restrict__ A, const u16* __restrict__ Bt,
    const float* __restrict__ bias, const void* __restrict__ res,
    void* __restrict__ C, int M, int N, int K, int moff,
    const int* __restrict__ flagp) {
    constexpr int BN = 2 * WN;
    constexpr int NJ = WN / 16;       // B-fragments per wave
    constexpr int NB = BN / 64;       // B staging chunks per thread
    const int f = *flagp;
    __shared__ __align__(16) u16 As[2][128 * 32];
    __shared__ __align__(16) u16 Bs[2][BN * 32];
    const int tid = threadIdx.x;
    const int m0 = blockIdx.x * 128, n0 = blockIdx.y * BN;
    const int wave = tid >> 6, lane = tid & 63;
    const int wm = (wave & 1) * 64, wn = (wave >> 1) * WN;
    const int lm = lane & 15, quad = lane >> 4;

    const int koff = (tid & 3) * 8;
    const int srow = tid >> 2;                       // 0..63
    const u16* gA[2];
    const u16* gB[NB];
#pragma unroll
    for (int i = 0; i < 2; i++)
        gA[i] = A + (size_t)(m0 + srow + i * 64) * K + koff;
#pragma unroll
    for (int i = 0; i < NB; i++)
        gB[i] = Bt + (size_t)(n0 + srow + i * 64) * K + koff;

    f32x4 acc[4][NJ] = {};

    auto stage = [&](int buf) {
#pragma unroll
        for (int i = 0; i < 2; i++) {
            gl_lds16(gA[i], &As[buf][(tid + i * 256) * 8]);
            gA[i] += 32;
        }
#pragma unroll
        for (int i = 0; i < NB; i++) {
            gl_lds16(gB[i], &Bs[buf][(tid + i * 256) * 8]);
            gB[i] += 32;
        }
    };
    auto compute = [&](int buf) {
        bf16x8 af[4], bfv[NJ];
#pragma unroll
        for (int i = 0; i < 4; i++)
            af[i] = *(const bf16x8*)&As[buf][(wm + i * 16 + lm) * 32 + quad * 8];
#pragma unroll
        for (int j = 0; j < NJ; j++)
            bfv[j] = *(const bf16x8*)&Bs[buf][(wn + j * 16 + lm) * 32 + quad * 8];
#pragma unroll
        for (int i = 0; i < 4; i++)
#pragma unroll
            for (int j = 0; j < NJ; j++)
                acc[i][j] = __builtin_amdgcn_mfma_f32_16x16x32_bf16(
                    af[i], bfv[j], acc[i][j], 0, 0, 0);
    };

    stage(0);                          // prologue: tile 0 in flight
    int cur = 0;
    for (int k0 = 32; k0 < K; k0 += 32) {
        __syncthreads();               // drains vmcnt: buf[cur] ready; prior
                                       // readers of buf[cur^1] are done
        stage(cur ^ 1);                // next tile flies during compute
        compute(cur);
        cur ^= 1;
    }
    __syncthreads();
    compute(cur);                      // epilogue tile (no prefetch)

    float bias_f[NJ];
#pragma unroll
    for (int j = 0; j < NJ; j++)
        bias_f[j] = bias[n0 + wn + j * 16 + lm];
#pragma unroll
    for (int i = 0; i < 4; i++) {
#pragma unroll
        for (int r = 0; r < 4; r++) {
            const int row = m0 + wm + i * 16 + quad * 4 + r;  // C/D: row=quad*4+reg
#pragma unroll
            for (int j = 0; j < NJ; j++) {
                int col = n0 + wn + j * 16 + lm;              // C/D: col=lane&15
                size_t rb;
                if (CSPLIT > 0) {
                    const int reg = col / CSPLIT;             // const div
                    rb = ((size_t)reg * M + moff + row) * (size_t)CSPLIT;
                    col -= reg * CSPLIT;
                } else {
                    rb = (size_t)(moff + row) * N;
                }
                float vv = acc[i][j][r] + bias_f[j];
                if (ACT == 1) vv = gelu_exact(vv);
                if (RES == 1) vv += b2f(((const u16*)res)[rb + col]);
                if (RES == 2) vv += loadDyn(res, rb + col, f);
                if (STORE == 0) ((u16*)C)[rb + col] = f2b(vv);
                else {
                    if (f) ((float*)C)[rb + col] = vv;
                    else   ((u16*)C)[rb + col] = f2b(vv);
                }
            }
        }
    }
}

// ---------------------------------------------------------------------------
// MFMA masked flash-attention. Block = (h, q-tile 64, b), 4 waves; wave w
// owns query rows w*16..+16. S=QK^T (MFMA), bitmask+online softmax in regs,
// P->LDS->A-frags, O += P V with V staged from the GLOBAL pre-transposed Vt.
// o may alias q.
// ---------------------------------------------------------------------------
__global__ __launch_bounds__(256) void attn_mfma_k(
    const u16* q, const u16* __restrict__ k,
    const u16* __restrict__ vt, const u64* __restrict__ mask, u16* o) {
    const int h = blockIdx.x, qg = blockIdx.y, b = blockIdx.z;
    const int q0 = qg * 64;
    const int tid = threadIdx.x;
    const int wave = tid >> 6, lane = tid & 63;
    const int lm = lane & 15, quad = lane >> 4;
    const int wm = wave * 16;
    const int bh = b * Hn + h;

    __shared__ __align__(16) u16 Qs[64 * 72];
    __shared__ __align__(16) u16 Ks[64 * 72];
    __shared__ __align__(16) u16 Vts[64 * 72];   // [dim][key]
    __shared__ __align__(16) u16 Ps[64 * 72];

    {
        const int row = tid >> 2, dc = (tid & 3) * 16;
        const u16* src = q + ((size_t)(b * Nn + q0 + row)) * Dn + h * HDn + dc;
        *(u16x8*)&Qs[row * 72 + dc]     = *(const u16x8*)src;
        *(u16x8*)&Qs[row * 72 + dc + 8] = *(const u16x8*)(src + 8);
    }

    float m_i[4], l_i[4];           // row = wm + quad*4 + r
#pragma unroll
    for (int r = 0; r < 4; r++) { m_i[r] = -3e38f; l_i[r] = 0.f; }
    f32x4 Oacc[4] = {};             // dim = j*16+lm

    for (int kb = 0; kb < Nn / 64; kb++) {
        const int kb0 = kb * 64;
        __syncthreads();   // prior iter's Ks/Vts/Ps reads done; Q staged (kb=0)
        {   // stage K rows + Vt dim-rows (both vectorized)
            const int row = tid >> 2, dc = (tid & 3) * 16;
            const u16* ksrc = k + ((size_t)(b * Nn + kb0 + row)) * Dn + h * HDn + dc;
            *(u16x8*)&Ks[row * 72 + dc]     = *(const u16x8*)ksrc;
            *(u16x8*)&Ks[row * 72 + dc + 8] = *(const u16x8*)(ksrc + 8);
            const int dim = tid >> 2, ks = (tid & 3) * 16;
            const u16* vsrc = vt + ((size_t)bh * HDn + dim) * Nn + kb0 + ks;
            *(u16x8*)&Vts[dim * 72 + ks]     = *(const u16x8*)vsrc;
            *(u16x8*)&Vts[dim * 72 + ks + 8] = *(const u16x8*)(vsrc + 8);
        }
        __syncthreads();
        // S = Q K^T (this wave's 16 rows x 64 keys)
        f32x4 sacc[4] = {};
#pragma unroll
        for (int s = 0; s < 2; s++) {
            bf16x8 aq = *(const bf16x8*)&Qs[(wm + lm) * 72 + s * 32 + quad * 8];
#pragma unroll
            for (int j = 0; j < 4; j++) {
                bf16x8 bk = *(const bf16x8*)&Ks[(j * 16 + lm) * 72 + s * 32 + quad * 8];
                sacc[j] = __builtin_amdgcn_mfma_f32_16x16x32_bf16(aq, bk, sacc[j], 0, 0, 0);
            }
        }
        // bitmask + scale + row max
        float pmax[4];
#pragma unroll
        for (int r = 0; r < 4; r++) {
            const u64 mrow = mask[(size_t)(b * Nn + q0 + wm + quad * 4 + r) * 8 + kb];
            float mx = -3e38f;
#pragma unroll
            for (int j = 0; j < 4; j++) {
                const int bit = (int)((mrow >> (j * 16 + lm)) & 1ull);
                float sc = bit ? sacc[j][r] * 0.125f : -3e38f;
                sacc[j][r] = sc;
                mx = fmaxf(mx, sc);
            }
            mx = fmaxf(mx, __shfl_xor(mx, 1, 64));
            mx = fmaxf(mx, __shfl_xor(mx, 2, 64));
            mx = fmaxf(mx, __shfl_xor(mx, 4, 64));
            mx = fmaxf(mx, __shfl_xor(mx, 8, 64));
            pmax[r] = mx;
        }
        // online update; all-masked rows keep O=0,l=0 (exp(0)=1 harmless)
        float alpha[4];
#pragma unroll
        for (int r = 0; r < 4; r++) {
            float newm = fmaxf(m_i[r], pmax[r]);
            alpha[r] = __expf(m_i[r] - newm);
            m_i[r] = newm;
            float s_ = 0.f;
#pragma unroll
            for (int j = 0; j < 4; j++) {
                float sc = sacc[j][r];
                float p = (sc > -1e30f) ? __expf(sc - newm) : 0.f;
                sacc[j][r] = p;
                s_ += p;
            }
            s_ += __shfl_xor(s_, 1, 64);
            s_ += __shfl_xor(s_, 2, 64);
            s_ += __shfl_xor(s_, 4, 64);
            s_ += __shfl_xor(s_, 8, 64);
            l_i[r] = l_i[r] * alpha[r] + s_;
        }
        // P (C-layout) -> LDS (A-layout source)
#pragma unroll
        for (int r = 0; r < 4; r++)
#pragma unroll
            for (int j = 0; j < 4; j++)
                Ps[(wm + quad * 4 + r) * 72 + j * 16 + lm] = f2b(sacc[j][r]);
#pragma unroll
        for (int j = 0; j < 4; j++)
#pragma unroll
            for (int r = 0; r < 4; r++) Oacc[j][r] *= alpha[r];
        __syncthreads();
        // O += P V   (B from Vt[dim][key]: contiguous b128)
#pragma unroll
        for (int s = 0; s < 2; s++) {
            bf16x8 ap = *(const bf16x8*)&Ps[(wm + lm) * 72 + s * 32 + quad * 8];
#pragma unroll
            for (int j = 0; j < 4; j++) {
                bf16x8 bv = *(const bf16x8*)&Vts[(j * 16 + lm) * 72 + s * 32 + quad * 8];
                Oacc[j] = __builtin_amdgcn_mfma_f32_16x16x32_bf16(ap, bv, Oacc[j], 0, 0, 0);
            }
        }
    }
    float inv[4];
#pragma unroll
    for (int r = 0; r < 4; r++) inv[r] = (l_i[r] > 0.f) ? 1.0f / l_i[r] : 0.f;
#pragma unroll
    for (int r = 0; r < 4; r++) {
        const int row = q0 + wm + quad * 4 + r;
        u16* dst = o + ((size_t)(b * Nn + row)) * Dn + h * HDn;
#pragma unroll
        for (int j = 0; j < 4; j++)
            dst[j * 16 + lm] = f2b(Oacc[j][r] * inv[r]);
    }
}

// ---------------------------------------------------------------------------
extern "C" void kernel_launch(void* const* d_in, const int* in_sizes, int n_in,
                              void* d_out, int out_size, void* d_ws,
                              size_t ws_size, hipStream_t stream) {
    const void* x   = d_in[0];
    const int* adj  = (const int*)d_in[1];
    const void* wq  = d_in[2];
    const void* bq  = d_in[3];
    const void* wk  = d_in[4];
    const void* bk  = d_in[5];
    const void* wv  = d_in[6];
    const void* bv  = d_in[7];
    const void* wo  = d_in[8];
    const void* bo  = d_in[9];
    const void* g1  = d_in[10];
    const void* b1  = d_in[11];
    const void* g2  = d_in[12];
    const void* b2  = d_in[13];
    const void* w1  = d_in[14];
    const void* bf1 = d_in[15];
    const void* w2  = d_in[16];
    const void* bf2 = d_in[17];

    // ---- workspace (~116 MiB) ----
    char* ws = (char*)d_ws;
    size_t off = 0;
    auto alloc = [&](size_t bytes) -> char* {
        char* p = ws + off;
        off += (bytes + 255) & ~(size_t)255;
        return p;
    };
    int* flag = (int*)alloc(4);
    u16* wqkvT = (u16*)alloc((size_t)3 * Dn * Dn * 2);     // [2304][768]
    u16* woT  = (u16*)alloc((size_t)Dn * Dn * 2);
    u16* w1T  = (u16*)alloc((size_t)Dn * DFn * 2);
    u16* w2T  = (u16*)alloc((size_t)Dn * DFn * 2);
    float* biasf = (float*)alloc(6912 * 4);                // packed fp32 biases
    u64* maskbuf = (u64*)alloc((size_t)Mn * 8 * 8);        // 1 MB
    const size_t S = (size_t)Mn * Dn * 2;                  // 25.17 MB (256-mult)
    u16* Rh = (u16*)alloc(S);   // LN1-h -> Vt -> LN2-h2
    u16* Rq = (u16*)alloc(S);   // Q -> attn-out -> hidden[lo]
    u16* Rk = (u16*)alloc(S);   // K -> hidden[hi]  (Rq+S == Rk: contiguous)
    u16* Rv = (u16*)alloc(S);   // V -> outb (WO out + residual)  (Rk+S == Rv)

    sniff_k<<<1, 256, 0, stream>>>((const u16*)x, flag);
    mask_build_k<<<Mn * 8 / 256, 256, 0, stream>>>(adj, maskbuf);
    pack_bias_k<<<27, 256, 0, stream>>>(bq, bk, bv, bo, bf1, bf2, biasf, flag);

    dim3 tb(32, 8);
    // fused QKV weight: rows 0..767 = wq^T, 768..1535 = wk^T, 1536..2303 = wv^T
    transpose_k<<<dim3(Dn / 32, Dn / 32), tb, 0, stream>>>(wq, wqkvT, Dn, Dn, flag);
    transpose_k<<<dim3(Dn / 32, Dn / 32), tb, 0, stream>>>(wk, wqkvT + (size_t)Dn * Dn, Dn, Dn, flag);
    transpose_k<<<dim3(Dn / 32, Dn / 32), tb, 0, stream>>>(wv, wqkvT + (size_t)2 * Dn * Dn, Dn, Dn, flag);
    transpose_k<<<dim3(Dn / 32, Dn / 32), tb, 0, stream>>>(wo, woT, Dn, Dn, flag);
    transpose_k<<<dim3(DFn / 32, Dn / 32), tb, 0, stream>>>(w1, w1T, Dn, DFn, flag);
    transpose_k<<<dim3(Dn / 32, DFn / 32), tb, 0, stream>>>(w2, w2T, DFn, Dn, flag);

    // LN1: x -> Rh
    ln_k<1><<<Mn / 8, 256, 0, stream>>>(x, g1, b1, Rh, flag);

    // fused QKV projection: [Mn][768] @ [768][2304] -> Rq|Rk|Rv (CSPLIT=768)
    gemm_bt<0, 0, 0, 64, Dn><<<dim3(Mn / 128, 3 * Dn / 128), 256, 0, stream>>>(
        Rh, wqkvT, biasf, nullptr, Rq, Mn, 3 * Dn, Dn, 0, flag);

    // Vt = V^T per (b,h): Rv -> Rh (Rh dead after QKV)
    vtrans_k<<<dim3(HDn / 32, Nn / 32, Bn * Hn), tb, 0, stream>>>(Rv, Rh);

    // attention: (Rq, Rk, Vt=Rh, mask) -> Rq (in-place over Q)
    attn_mfma_k<<<dim3(Hn, Nn / 64, Bn), 256, 0, stream>>>(Rq, Rk, Rh, maskbuf, Rq);

    // outb = attn @ wo + bo + x -> Rv  (V dead after vtrans)
    gemm_bt<0, 2, 0, 64, 0><<<dim3(Mn / 128, Dn / 128), 256, 0, stream>>>(
        Rq, woT, biasf + 2304, x, Rv, Mn, Dn, Dn, 0, flag);

    // LN2: Rv -> Rh (Vt dead after attn)
    ln_k<0><<<Mn / 8, 256, 0, stream>>>(Rv, g2, b2, Rh, flag);

    // FFN in 2 M-chunks of 8192; hidden (50.3 MB) spans Rq+Rk
    u16* hidden = Rq;
    for (int c = 0; c < Mn / MCHUNK; c++) {
        gemm_bt<1, 0, 0, 64, 0><<<dim3(MCHUNK / 128, DFn / 128), 256, 0, stream>>>(
            Rh + (size_t)c * MCHUNK * Dn, w1T, biasf + 3072, nullptr, hidden,
            MCHUNK, DFn, Dn, 0, flag);
        gemm_bt<0, 1, 1, 64, 0><<<dim3(MCHUNK / 128, Dn / 128), 256, 0, stream>>>(
            hidden, w2T, biasf + 6144, Rv, d_out, MCHUNK, Dn, DFn, c * MCHUNK, flag);
    }
}

// Round 2
// 679.697 us; speedup vs baseline: 1.4505x; 1.1667x over previous
//
#include <hip/hip_runtime.h>

// ---------------------------------------------------------------------------
// DenseGATLayer: LN1 -> fused QKV proj -> adj-masked MHA -> WO proj + residual
//                -> LN2 -> GELU FFN -> residual
// B=32 N=512 D=768 H=12 HD=64. bf16 MFMA, fp32 accumulation.
// R6: double-buffered single-barrier GEMM K-loop, 128x128 tiles, fused QKV.
// R7: sniff_k was the top dispatch (120 us, single block, scalar loads,
// latency-serialized at 1.1 GB/s). Now 64 blocks x u16x8 loads + wave-reduce
// + atomicAdd; flag zeroed via hipMemsetAsync; consumers threshold >32.
// ---------------------------------------------------------------------------

#define Bn 32
#define Nn 512
#define Dn 768
#define Hn 12
#define HDn 64
#define Mn (Bn * Nn)      // 16384 rows
#define DFn 3072          // FFN hidden
#define MCHUNK 8192       // FFN M-chunk rows (hidden = 50.3 MB -> Rq+Rk)

typedef unsigned short u16;
typedef unsigned long long u64;
typedef short bf16x8 __attribute__((ext_vector_type(8)));
typedef float f32x4 __attribute__((ext_vector_type(4)));
typedef unsigned short u16x8 __attribute__((ext_vector_type(8)));

__device__ __forceinline__ float b2f(u16 u) {
    return __uint_as_float(((unsigned int)u) << 16);
}
__device__ __forceinline__ u16 f2b(float f) {
    unsigned int u = __float_as_uint(f);
    u += 0x7fffu + ((u >> 16) & 1u);   // RNE
    return (u16)(u >> 16);
}
__device__ __forceinline__ float loadDyn(const void* p, size_t i, int f) {
    return f ? ((const float*)p)[i] : b2f(((const u16*)p)[i]);
}
__device__ __forceinline__ float gelu_exact(float x) {
    return 0.5f * x * (1.0f + erff(x * 0.70710678118654752f));
}

// async global->LDS, 16B/lane; LDS dest = wave-uniform base + lane*16.
__device__ __forceinline__ void gl_lds16(const u16* g, u16* l) {
    __builtin_amdgcn_global_load_lds(
        (const __attribute__((address_space(1))) void*)(unsigned long long)(const void*)g,
        (__attribute__((address_space(3))) void*)(unsigned)(unsigned long long)(void*)l,
        16, 0, 0);
}

// ---------------------------------------------------------------------------
// Dtype sniffer (bf16 vs fp32 inputs). Counts u16 words whose bf16-exponent
// field is all-ones (NaN/Inf pattern); fp32 mantissa halves hit it ~1/256.
// Parallel: 64 blocks x 256 threads x u16x8 = 131072 elems, wave-reduce,
// one atomicAdd per wave. flag pre-zeroed by hipMemsetAsync; consumers
// treat f = (*flag > 32).
// ---------------------------------------------------------------------------
__global__ __launch_bounds__(256) void sniff_k(const u16* __restrict__ x,
                                               int* __restrict__ flag) {
    const int idx = blockIdx.x * 256 + threadIdx.x;
    u16x8 a = *(const u16x8*)&x[(size_t)idx * 8];
    int cnt = 0;
#pragma unroll
    for (int e = 0; e < 8; e++)
        cnt += ((a[e] & 0x7F80) == 0x7F80) ? 1 : 0;
#pragma unroll
    for (int off = 1; off <= 32; off <<= 1) cnt += __shfl_xor(cnt, off, 64);
    if ((threadIdx.x & 63) == 0 && cnt > 0) atomicAdd(flag, cnt);
}

__device__ __forceinline__ int flagval(const int* flagp) {
    return (*flagp > 32) ? 1 : 0;
}

// ---------------------------------------------------------------------------
// Pack all bias vectors to fp32: [bq 768 | bk 768 | bv 768 | bo 768 |
// bf1 3072 | bf2 768] = 6912 floats. Removes dyn-dtype loads from GEMM epi.
// ---------------------------------------------------------------------------
__global__ __launch_bounds__(256) void pack_bias_k(
    const void* __restrict__ bq, const void* __restrict__ bk,
    const void* __restrict__ bv, const void* __restrict__ bo,
    const void* __restrict__ bf1, const void* __restrict__ bf2,
    float* __restrict__ out, const int* __restrict__ flagp) {
    const int f = flagval(flagp);
    const int i = blockIdx.x * 256 + threadIdx.x;
    if (i >= 6912) return;
    const void* src;
    int off;
    if (i < 768)       { src = bq;  off = i; }
    else if (i < 1536) { src = bk;  off = i - 768; }
    else if (i < 2304) { src = bv;  off = i - 1536; }
    else if (i < 3072) { src = bo;  off = i - 2304; }
    else if (i < 6144) { src = bf1; off = i - 3072; }
    else               { src = bf2; off = i - 6144; }
    out[i] = loadDyn(src, off, f);
}

// ---------------------------------------------------------------------------
// adj -> bitmask: mask[row*8 + seg] bit j = (adj[row][seg*64+j] != 0).
// ---------------------------------------------------------------------------
__global__ __launch_bounds__(256) void mask_build_k(
    const int* __restrict__ adj, u64* __restrict__ mask) {
    const int idx = blockIdx.x * 256 + threadIdx.x;   // Mn*8 = 131072 ids
    const size_t base = (size_t)(idx >> 3) * Nn + (size_t)(idx & 7) * 64;
    const int4* p = (const int4*)(adj + base);
    u64 m = 0;
#pragma unroll
    for (int c = 0; c < 16; c++) {
        int4 a = p[c];
        if (a.x) m |= 1ull << (c * 4 + 0);
        if (a.y) m |= 1ull << (c * 4 + 1);
        if (a.z) m |= 1ull << (c * 4 + 2);
        if (a.w) m |= 1ull << (c * 4 + 3);
    }
    mask[idx] = m;
}

// ---------------------------------------------------------------------------
// Transpose raw weight -> canonical bf16: out[c][r] = in[r][c]
// ---------------------------------------------------------------------------
__global__ __launch_bounds__(256) void transpose_k(
    const void* __restrict__ in, u16* __restrict__ out, int R, int C,
    const int* __restrict__ flagp) {
    const int f = flagval(flagp);
    __shared__ u16 tile[32][33];
    int c0 = blockIdx.x * 32, r0 = blockIdx.y * 32;
    int tx = threadIdx.x, ty = threadIdx.y;  // 32 x 8
#pragma unroll
    for (int i = 0; i < 32; i += 8)
        tile[ty + i][tx] = f2b(loadDyn(in, (size_t)(r0 + ty + i) * C + c0 + tx, f));
    __syncthreads();
#pragma unroll
    for (int i = 0; i < 32; i += 8)
        out[(size_t)(c0 + ty + i) * R + r0 + tx] = tile[tx][ty + i];
}

// ---------------------------------------------------------------------------
// V [b][n][h][d] -> Vt [b*H+h][d][n]
// ---------------------------------------------------------------------------
__global__ __launch_bounds__(256) void vtrans_k(
    const u16* __restrict__ v, u16* __restrict__ vt) {
    __shared__ u16 tile[32][33];
    const int bh = blockIdx.z;                 // b*Hn + h
    const int d0 = blockIdx.x * 32;            // 0 / 32
    const int n0 = blockIdx.y * 32;
    const int b = bh / Hn, h = bh % Hn;
    const int tx = threadIdx.x, ty = threadIdx.y;   // 32 x 8
#pragma unroll
    for (int i = 0; i < 32; i += 8)
        tile[ty + i][tx] =
            v[(size_t)(b * Nn + n0 + ty + i) * Dn + h * HDn + d0 + tx];
    __syncthreads();
#pragma unroll
    for (int i = 0; i < 32; i += 8)
        vt[((size_t)bh * HDn + d0 + ty + i) * Nn + n0 + tx] = tile[tx][ty + i];
}

// ---------------------------------------------------------------------------
// LayerNorm over D=768. 8 rows/block, 32 lanes/row, u16x8 vector loads.
// ---------------------------------------------------------------------------
template <int XDYN>
__global__ __launch_bounds__(256) void ln_k(
    const void* __restrict__ x, const void* __restrict__ g,
    const void* __restrict__ b, u16* __restrict__ y,
    const int* __restrict__ flagp) {
    const int f = flagval(flagp);
    const int t = threadIdx.x;
    const int row = blockIdx.x * 8 + (t >> 5);
    const int l32 = t & 31;
    const size_t base = (size_t)row * Dn;
    float v[24];
    if (XDYN == 0 || f == 0) {   // bf16 path (ws buffers always bf16)
        const u16* xp = (const u16*)x;
#pragma unroll
        for (int kk = 0; kk < 3; kk++) {
            u16x8 a = *(const u16x8*)&xp[base + kk * 256 + l32 * 8];
#pragma unroll
            for (int e = 0; e < 8; e++) v[kk * 8 + e] = b2f(a[e]);
        }
    } else {
#pragma unroll
        for (int kk = 0; kk < 3; kk++)
#pragma unroll
            for (int e = 0; e < 8; e++)
                v[kk * 8 + e] = loadDyn(x, base + kk * 256 + l32 * 8 + e, f);
    }
    float s = 0.f;
#pragma unroll
    for (int i = 0; i < 24; i++) s += v[i];
#pragma unroll
    for (int off = 1; off <= 16; off <<= 1) s += __shfl_xor(s, off, 64);
    const float mu = s * (1.0f / Dn);
    float d2 = 0.f;
#pragma unroll
    for (int i = 0; i < 24; i++) { float d = v[i] - mu; d2 += d * d; }
#pragma unroll
    for (int off = 1; off <= 16; off <<= 1) d2 += __shfl_xor(d2, off, 64);
    const float rstd = rsqrtf(d2 * (1.0f / Dn) + 1e-5f);
#pragma unroll
    for (int kk = 0; kk < 3; kk++) {
        const int c0 = kk * 256 + l32 * 8;
        u16x8 o;
        if (f == 0) {
            u16x8 gv = *(const u16x8*)&((const u16*)g)[c0];
            u16x8 bv = *(const u16x8*)&((const u16*)b)[c0];
#pragma unroll
            for (int e = 0; e < 8; e++)
                o[e] = f2b((v[kk * 8 + e] - mu) * rstd * b2f(gv[e]) + b2f(bv[e]));
        } else {
#pragma unroll
            for (int e = 0; e < 8; e++)
                o[e] = f2b((v[kk * 8 + e] - mu) * rstd * loadDyn(g, c0 + e, f)
                           + loadDyn(b, c0 + e, f));
        }
        *(u16x8*)&y[base + c0] = o;
    }
}

// ---------------------------------------------------------------------------
// GEMM: C[moff+M][N] = epi( A[M][K] @ Bt[N][K]^T + bias (+res) ).
// Block tile 128 x (2*WN), BK=32, 4 waves (2x2); wave tile 64 x WN.
// Double-buffered LDS, ONE barrier per K-step: stage(next) issues
// global_load_lds into buf^1 BEFORE the ds_read+MFMA of buf, so the loads'
// latency hides under the compute; the barrier's implicit vmcnt(0)/lgkmcnt(0)
// drain at the top of the next iteration is the only wait.
// CSPLIT>0: output columns routed in CSPLIT-wide regions to consecutive
// [M][CSPLIT] buffers (fused QKV -> contiguous Rq/Rk/Rv).
// ---------------------------------------------------------------------------
template <int ACT, int RES, int STORE, int WN, int CSPLIT>
__global__ __launch_bounds__(256, 3) void gemm_bt(
    const u16* __restrict__ A, const u16* __restrict__ Bt,
    const float* __restrict__ bias, const void* __restrict__ res,
    void* __restrict__ C, int M, int N, int K, int moff,
    const int* __restrict__ flagp) {
    constexpr int BN = 2 * WN;
    constexpr int NJ = WN / 16;       // B-fragments per wave
    constexpr int NB = BN / 64;       // B staging chunks per thread
    const int f = flagval(flagp);
    __shared__ __align__(16) u16 As[2][128 * 32];
    __shared__ __align__(16) u16 Bs[2][BN * 32];
    const int tid = threadIdx.x;
    const int m0 = blockIdx.x * 128, n0 = blockIdx.y * BN;
    const int wave = tid >> 6, lane = tid & 63;
    const int wm = (wave & 1) * 64, wn = (wave >> 1) * WN;
    const int lm = lane & 15, quad = lane >> 4;

    const int koff = (tid & 3) * 8;
    const int srow = tid >> 2;                       // 0..63
    const u16* gA[2];
    const u16* gB[NB];
#pragma unroll
    for (int i = 0; i < 2; i++)
        gA[i] = A + (size_t)(m0 + srow + i * 64) * K + koff;
#pragma unroll
    for (int i = 0; i < NB; i++)
        gB[i] = Bt + (size_t)(n0 + srow + i * 64) * K + koff;

    f32x4 acc[4][NJ] = {};

    auto stage = [&](int buf) {
#pragma unroll
        for (int i = 0; i < 2; i++) {
            gl_lds16(gA[i], &As[buf][(tid + i * 256) * 8]);
            gA[i] += 32;
        }
#pragma unroll
        for (int i = 0; i < NB; i++) {
            gl_lds16(gB[i], &Bs[buf][(tid + i * 256) * 8]);
            gB[i] += 32;
        }
    };
    auto compute = [&](int buf) {
        bf16x8 af[4], bfv[NJ];
#pragma unroll
        for (int i = 0; i < 4; i++)
            af[i] = *(const bf16x8*)&As[buf][(wm + i * 16 + lm) * 32 + quad * 8];
#pragma unroll
        for (int j = 0; j < NJ; j++)
            bfv[j] = *(const bf16x8*)&Bs[buf][(wn + j * 16 + lm) * 32 + quad * 8];
#pragma unroll
        for (int i = 0; i < 4; i++)
#pragma unroll
            for (int j = 0; j < NJ; j++)
                acc[i][j] = __builtin_amdgcn_mfma_f32_16x16x32_bf16(
                    af[i], bfv[j], acc[i][j], 0, 0, 0);
    };

    stage(0);                          // prologue: tile 0 in flight
    int cur = 0;
    for (int k0 = 32; k0 < K; k0 += 32) {
        __syncthreads();               // drains vmcnt: buf[cur] ready; prior
                                       // readers of buf[cur^1] are done
        stage(cur ^ 1);                // next tile flies during compute
        compute(cur);
        cur ^= 1;
    }
    __syncthreads();
    compute(cur);                      // epilogue tile (no prefetch)

    float bias_f[NJ];
#pragma unroll
    for (int j = 0; j < NJ; j++)
        bias_f[j] = bias[n0 + wn + j * 16 + lm];
#pragma unroll
    for (int i = 0; i < 4; i++) {
#pragma unroll
        for (int r = 0; r < 4; r++) {
            const int row = m0 + wm + i * 16 + quad * 4 + r;  // C/D: row=quad*4+reg
#pragma unroll
            for (int j = 0; j < NJ; j++) {
                int col = n0 + wn + j * 16 + lm;              // C/D: col=lane&15
                size_t rb;
                if (CSPLIT > 0) {
                    const int reg = col / CSPLIT;             // const div
                    rb = ((size_t)reg * M + moff + row) * (size_t)CSPLIT;
                    col -= reg * CSPLIT;
                } else {
                    rb = (size_t)(moff + row) * N;
                }
                float vv = acc[i][j][r] + bias_f[j];
                if (ACT == 1) vv = gelu_exact(vv);
                if (RES == 1) vv += b2f(((const u16*)res)[rb + col]);
                if (RES == 2) vv += loadDyn(res, rb + col, f);
                if (STORE == 0) ((u16*)C)[rb + col] = f2b(vv);
                else {
                    if (f) ((float*)C)[rb + col] = vv;
                    else   ((u16*)C)[rb + col] = f2b(vv);
                }
            }
        }
    }
}

// ---------------------------------------------------------------------------
// MFMA masked flash-attention. Block = (h, q-tile 64, b), 4 waves; wave w
// owns query rows w*16..+16. S=QK^T (MFMA), bitmask+online softmax in regs,
// P->LDS->A-frags, O += P V with V staged from the GLOBAL pre-transposed Vt.
// o may alias q.
// ---------------------------------------------------------------------------
__global__ __launch_bounds__(256) void attn_mfma_k(
    const u16* q, const u16* __restrict__ k,
    const u16* __restrict__ vt, const u64* __restrict__ mask, u16* o) {
    const int h = blockIdx.x, qg = blockIdx.y, b = blockIdx.z;
    const int q0 = qg * 64;
    const int tid = threadIdx.x;
    const int wave = tid >> 6, lane = tid & 63;
    const int lm = lane & 15, quad = lane >> 4;
    const int wm = wave * 16;
    const int bh = b * Hn + h;

    __shared__ __align__(16) u16 Qs[64 * 72];
    __shared__ __align__(16) u16 Ks[64 * 72];
    __shared__ __align__(16) u16 Vts[64 * 72];   // [dim][key]
    __shared__ __align__(16) u16 Ps[64 * 72];

    {
        const int row = tid >> 2, dc = (tid & 3) * 16;
        const u16* src = q + ((size_t)(b * Nn + q0 + row)) * Dn + h * HDn + dc;
        *(u16x8*)&Qs[row * 72 + dc]     = *(const u16x8*)src;
        *(u16x8*)&Qs[row * 72 + dc + 8] = *(const u16x8*)(src + 8);
    }

    float m_i[4], l_i[4];           // row = wm + quad*4 + r
#pragma unroll
    for (int r = 0; r < 4; r++) { m_i[r] = -3e38f; l_i[r] = 0.f; }
    f32x4 Oacc[4] = {};             // dim = j*16+lm

    for (int kb = 0; kb < Nn / 64; kb++) {
        const int kb0 = kb * 64;
        __syncthreads();   // prior iter's Ks/Vts/Ps reads done; Q staged (kb=0)
        {   // stage K rows + Vt dim-rows (both vectorized)
            const int row = tid >> 2, dc = (tid & 3) * 16;
            const u16* ksrc = k + ((size_t)(b * Nn + kb0 + row)) * Dn + h * HDn + dc;
            *(u16x8*)&Ks[row * 72 + dc]     = *(const u16x8*)ksrc;
            *(u16x8*)&Ks[row * 72 + dc + 8] = *(const u16x8*)(ksrc + 8);
            const int dim = tid >> 2, ks = (tid & 3) * 16;
            const u16* vsrc = vt + ((size_t)bh * HDn + dim) * Nn + kb0 + ks;
            *(u16x8*)&Vts[dim * 72 + ks]     = *(const u16x8*)vsrc;
            *(u16x8*)&Vts[dim * 72 + ks + 8] = *(const u16x8*)(vsrc + 8);
        }
        __syncthreads();
        // S = Q K^T (this wave's 16 rows x 64 keys)
        f32x4 sacc[4] = {};
#pragma unroll
        for (int s = 0; s < 2; s++) {
            bf16x8 aq = *(const bf16x8*)&Qs[(wm + lm) * 72 + s * 32 + quad * 8];
#pragma unroll
            for (int j = 0; j < 4; j++) {
                bf16x8 bk = *(const bf16x8*)&Ks[(j * 16 + lm) * 72 + s * 32 + quad * 8];
                sacc[j] = __builtin_amdgcn_mfma_f32_16x16x32_bf16(aq, bk, sacc[j], 0, 0, 0);
            }
        }
        // bitmask + scale + row max
        float pmax[4];
#pragma unroll
        for (int r = 0; r < 4; r++) {
            const u64 mrow = mask[(size_t)(b * Nn + q0 + wm + quad * 4 + r) * 8 + kb];
            float mx = -3e38f;
#pragma unroll
            for (int j = 0; j < 4; j++) {
                const int bit = (int)((mrow >> (j * 16 + lm)) & 1ull);
                float sc = bit ? sacc[j][r] * 0.125f : -3e38f;
                sacc[j][r] = sc;
                mx = fmaxf(mx, sc);
            }
            mx = fmaxf(mx, __shfl_xor(mx, 1, 64));
            mx = fmaxf(mx, __shfl_xor(mx, 2, 64));
            mx = fmaxf(mx, __shfl_xor(mx, 4, 64));
            mx = fmaxf(mx, __shfl_xor(mx, 8, 64));
            pmax[r] = mx;
        }
        // online update; all-masked rows keep O=0,l=0 (exp(0)=1 harmless)
        float alpha[4];
#pragma unroll
        for (int r = 0; r < 4; r++) {
            float newm = fmaxf(m_i[r], pmax[r]);
            alpha[r] = __expf(m_i[r] - newm);
            m_i[r] = newm;
            float s_ = 0.f;
#pragma unroll
            for (int j = 0; j < 4; j++) {
                float sc = sacc[j][r];
                float p = (sc > -1e30f) ? __expf(sc - newm) : 0.f;
                sacc[j][r] = p;
                s_ += p;
            }
            s_ += __shfl_xor(s_, 1, 64);
            s_ += __shfl_xor(s_, 2, 64);
            s_ += __shfl_xor(s_, 4, 64);
            s_ += __shfl_xor(s_, 8, 64);
            l_i[r] = l_i[r] * alpha[r] + s_;
        }
        // P (C-layout) -> LDS (A-layout source)
#pragma unroll
        for (int r = 0; r < 4; r++)
#pragma unroll
            for (int j = 0; j < 4; j++)
                Ps[(wm + quad * 4 + r) * 72 + j * 16 + lm] = f2b(sacc[j][r]);
#pragma unroll
        for (int j = 0; j < 4; j++)
#pragma unroll
            for (int r = 0; r < 4; r++) Oacc[j][r] *= alpha[r];
        __syncthreads();
        // O += P V   (B from Vt[dim][key]: contiguous b128)
#pragma unroll
        for (int s = 0; s < 2; s++) {
            bf16x8 ap = *(const bf16x8*)&Ps[(wm + lm) * 72 + s * 32 + quad * 8];
#pragma unroll
            for (int j = 0; j < 4; j++) {
                bf16x8 bv = *(const bf16x8*)&Vts[(j * 16 + lm) * 72 + s * 32 + quad * 8];
                Oacc[j] = __builtin_amdgcn_mfma_f32_16x16x32_bf16(ap, bv, Oacc[j], 0, 0, 0);
            }
        }
    }
    float inv[4];
#pragma unroll
    for (int r = 0; r < 4; r++) inv[r] = (l_i[r] > 0.f) ? 1.0f / l_i[r] : 0.f;
#pragma unroll
    for (int r = 0; r < 4; r++) {
        const int row = q0 + wm + quad * 4 + r;
        u16* dst = o + ((size_t)(b * Nn + row)) * Dn + h * HDn;
#pragma unroll
        for (int j = 0; j < 4; j++)
            dst[j * 16 + lm] = f2b(Oacc[j][r] * inv[r]);
    }
}

// ---------------------------------------------------------------------------
extern "C" void kernel_launch(void* const* d_in, const int* in_sizes, int n_in,
                              void* d_out, int out_size, void* d_ws,
                              size_t ws_size, hipStream_t stream) {
    const void* x   = d_in[0];
    const int* adj  = (const int*)d_in[1];
    const void* wq  = d_in[2];
    const void* bq  = d_in[3];
    const void* wk  = d_in[4];
    const void* bk  = d_in[5];
    const void* wv  = d_in[6];
    const void* bv  = d_in[7];
    const void* wo  = d_in[8];
    const void* bo  = d_in[9];
    const void* g1  = d_in[10];
    const void* b1  = d_in[11];
    const void* g2  = d_in[12];
    const void* b2  = d_in[13];
    const void* w1  = d_in[14];
    const void* bf1 = d_in[15];
    const void* w2  = d_in[16];
    const void* bf2 = d_in[17];

    // ---- workspace (~116 MiB) ----
    char* ws = (char*)d_ws;
    size_t off = 0;
    auto alloc = [&](size_t bytes) -> char* {
        char* p = ws + off;
        off += (bytes + 255) & ~(size_t)255;
        return p;
    };
    int* flag = (int*)alloc(4);
    u16* wqkvT = (u16*)alloc((size_t)3 * Dn * Dn * 2);     // [2304][768]
    u16* woT  = (u16*)alloc((size_t)Dn * Dn * 2);
    u16* w1T  = (u16*)alloc((size_t)Dn * DFn * 2);
    u16* w2T  = (u16*)alloc((size_t)Dn * DFn * 2);
    float* biasf = (float*)alloc(6912 * 4);                // packed fp32 biases
    u64* maskbuf = (u64*)alloc((size_t)Mn * 8 * 8);        // 1 MB
    const size_t S = (size_t)Mn * Dn * 2;                  // 25.17 MB (256-mult)
    u16* Rh = (u16*)alloc(S);   // LN1-h -> Vt -> LN2-h2
    u16* Rq = (u16*)alloc(S);   // Q -> attn-out -> hidden[lo]
    u16* Rk = (u16*)alloc(S);   // K -> hidden[hi]  (Rq+S == Rk: contiguous)
    u16* Rv = (u16*)alloc(S);   // V -> outb (WO out + residual)  (Rk+S == Rv)

    hipMemsetAsync(flag, 0, 4, stream);
    sniff_k<<<64, 256, 0, stream>>>((const u16*)x, flag);
    mask_build_k<<<Mn * 8 / 256, 256, 0, stream>>>(adj, maskbuf);
    pack_bias_k<<<27, 256, 0, stream>>>(bq, bk, bv, bo, bf1, bf2, biasf, flag);

    dim3 tb(32, 8);
    // fused QKV weight: rows 0..767 = wq^T, 768..1535 = wk^T, 1536..2303 = wv^T
    transpose_k<<<dim3(Dn / 32, Dn / 32), tb, 0, stream>>>(wq, wqkvT, Dn, Dn, flag);
    transpose_k<<<dim3(Dn / 32, Dn / 32), tb, 0, stream>>>(wk, wqkvT + (size_t)Dn * Dn, Dn, Dn, flag);
    transpose_k<<<dim3(Dn / 32, Dn / 32), tb, 0, stream>>>(wv, wqkvT + (size_t)2 * Dn * Dn, Dn, Dn, flag);
    transpose_k<<<dim3(Dn / 32, Dn / 32), tb, 0, stream>>>(wo, woT, Dn, Dn, flag);
    transpose_k<<<dim3(DFn / 32, Dn / 32), tb, 0, stream>>>(w1, w1T, Dn, DFn, flag);
    transpose_k<<<dim3(Dn / 32, DFn / 32), tb, 0, stream>>>(w2, w2T, DFn, Dn, flag);

    // LN1: x -> Rh
    ln_k<1><<<Mn / 8, 256, 0, stream>>>(x, g1, b1, Rh, flag);

    // fused QKV projection: [Mn][768] @ [768][2304] -> Rq|Rk|Rv (CSPLIT=768)
    gemm_bt<0, 0, 0, 64, Dn><<<dim3(Mn / 128, 3 * Dn / 128), 256, 0, stream>>>(
        Rh, wqkvT, biasf, nullptr, Rq, Mn, 3 * Dn, Dn, 0, flag);

    // Vt = V^T per (b,h): Rv -> Rh (Rh dead after QKV)
    vtrans_k<<<dim3(HDn / 32, Nn / 32, Bn * Hn), tb, 0, stream>>>(Rv, Rh);

    // attention: (Rq, Rk, Vt=Rh, mask) -> Rq (in-place over Q)
    attn_mfma_k<<<dim3(Hn, Nn / 64, Bn), 256, 0, stream>>>(Rq, Rk, Rh, maskbuf, Rq);

    // outb = attn @ wo + bo + x -> Rv  (V dead after vtrans)
    gemm_bt<0, 2, 0, 64, 0><<<dim3(Mn / 128, Dn / 128), 256, 0, stream>>>(
        Rq, woT, biasf + 2304, x, Rv, Mn, Dn, Dn, 0, flag);

    // LN2: Rv -> Rh (Vt dead after attn)
    ln_k<0><<<Mn / 8, 256, 0, stream>>>(Rv, g2, b2, Rh, flag);

    // FFN in 2 M-chunks of 8192; hidden (50.3 MB) spans Rq+Rk
    u16* hidden = Rq;
    for (int c = 0; c < Mn / MCHUNK; c++) {
        gemm_bt<1, 0, 0, 64, 0><<<dim3(MCHUNK / 128, DFn / 128), 256, 0, stream>>>(
            Rh + (size_t)c * MCHUNK * Dn, w1T, biasf + 3072, nullptr, hidden,
            MCHUNK, DFn, Dn, 0, flag);
        gemm_bt<0, 1, 1, 64, 0><<<dim3(MCHUNK / 128, Dn / 128), 256, 0, stream>>>(
            hidden, w2T, biasf + 6144, Rv, d_out, MCHUNK, Dn, DFn, c * MCHUNK, flag);
    }
}